// Round 5
// baseline (231.401 us; speedup 1.0000x reference)
//
#include <hip/hip_runtime.h>
#include <hip/hip_bf16.h>

#define B_   4
#define LQ_  900
#define D_   256
#define NH_  8
#define DH_  32
#define NL_  4
#define NP_  4
#define DFF_ 1024
#define LIN_ 21760
#define MQ_  (LQ_*B_)    // 3600
#define MV_  (LIN_*B_)   // 87040

typedef __attribute__((ext_vector_type(8))) short bh8;
typedef __attribute__((ext_vector_type(4))) float f32x4;

__device__ __forceinline__ short bf16b(float f) {
    __hip_bfloat16 h = __float2bfloat16(f);
    return *reinterpret_cast<short*>(&h);
}

__device__ __forceinline__ void gload_lds16(const void* g, void* l) {
    __builtin_amdgcn_global_load_lds(
        (const __attribute__((address_space(1))) unsigned int*)g,
        (__attribute__((address_space(3))) unsigned int*)l, 16, 0, 0);
}

// ---- W_val -> bf16 "LDS image": 4 chunks of 32 KB, swizzled rows ----
__global__ __launch_bounds__(256)
void wconv_k(const float* __restrict__ W, unsigned char* __restrict__ img)
{
    const int idx = blockIdx.x*256 + threadIdx.x;   // 16384 threads
    const int n  = idx >> 6;          // 0..255
    const int k0 = (idx & 63) * 4;    // 0..252
    const int kt = k0 >> 6;
    const int k2 = k0 & 63;
    float4 v = *reinterpret_cast<const float4*>(&W[(size_t)n*256 + k0]);
    short4 s = { bf16b(v.x), bf16b(v.y), bf16b(v.z), bf16b(v.w) };
    const int off = kt*32768 + ((n*128 + k2*2) ^ ((n & 7) << 4));
    *reinterpret_cast<short4*>(img + off) = s;
}

// ---------------- value projection: W-resident-in-LDS, barrier-free K loop ----------------
// BM=256 rows/block, 1024 threads (16 waves as 4x4), full N=256, full K=256.
__global__ __launch_bounds__(1024, 4)
void val_gemm_k(const float* __restrict__ A, const unsigned char* __restrict__ Wimg,
                const float* __restrict__ bias, unsigned short* __restrict__ C,
                const unsigned char* __restrict__ mask)
{
    __shared__ __align__(16) unsigned char Wl[131072];   // full W bf16, image layout

    const int tid  = threadIdx.x;
    const int lane = tid & 63;
    const int wid  = tid >> 6;     // 0..15
    const int wr   = wid >> 2;     // 0..3
    const int wc   = wid & 3;      // 0..3
    const int m0   = blockIdx.x * 256;
    const int r16  = lane & 15;
    const int g    = lane >> 4;    // 0..3

    // prologue: Wimg -> Wl, linear, 128 B/thread
    {
        const unsigned char* src = Wimg + wid*8192 + lane*16;
        char* dst = (char*)Wl + wid*8192;
        #pragma unroll
        for (int j = 0; j < 8; ++j) gload_lds16(src + j*1024, dst + j*1024);
    }

    // A row base pointers (MFMA A-frag: row = base + (lane&15), k = g*8..g*8+7)
    const float* arow[4];
    #pragma unroll
    for (int mf = 0; mf < 4; ++mf)
        arow[mf] = A + (size_t)(m0 + wr*64 + mf*16 + r16)*256 + g*8;

    int bofs[4], bswz[4];
    #pragma unroll
    for (int nf = 0; nf < 4; ++nf) {
        const int col = wc*64 + nf*16 + r16;
        bofs[nf] = col*128;
        bswz[nf] = (col & 7) << 4;
    }

    f32x4 acc[4][4];
    #pragma unroll
    for (int i = 0; i < 4; ++i)
        #pragma unroll
        for (int j = 0; j < 4; ++j) acc[i][j] = (f32x4){0.f,0.f,0.f,0.f};

    __syncthreads();   // W resident; only barrier in the kernel

    #pragma unroll
    for (int kq = 0; kq < 8; ++kq) {          // 8 x K=32
        const int k0 = kq * 32;
        bh8 af[4];
        #pragma unroll
        for (int mf = 0; mf < 4; ++mf) {
            float4 v0 = *reinterpret_cast<const float4*>(arow[mf] + k0);
            float4 v1 = *reinterpret_cast<const float4*>(arow[mf] + k0 + 4);
            af[mf] = (bh8){ bf16b(v0.x), bf16b(v0.y), bf16b(v0.z), bf16b(v0.w),
                            bf16b(v1.x), bf16b(v1.y), bf16b(v1.z), bf16b(v1.w) };
        }
        bh8 bf[4];
        #pragma unroll
        for (int nf = 0; nf < 4; ++nf) {
            const int addr = (kq >> 1)*32768 + bofs[nf] + ((((kq & 1)*64) + g*16) ^ bswz[nf]);
            bf[nf] = *reinterpret_cast<const bh8*>(Wl + addr);
        }
        #pragma unroll
        for (int mf = 0; mf < 4; ++mf)
            #pragma unroll
            for (int nf = 0; nf < 4; ++nf)
                acc[mf][nf] = __builtin_amdgcn_mfma_f32_16x16x32_bf16(af[mf], bf[nf], acc[mf][nf], 0, 0, 0);
    }

    float bv[4];
    #pragma unroll
    for (int nf = 0; nf < 4; ++nf) bv[nf] = bias[wc*64 + nf*16 + r16];

    #pragma unroll
    for (int mf = 0; mf < 4; ++mf) {
        #pragma unroll
        for (int r = 0; r < 4; ++r) {
            const int gm = m0 + wr*64 + mf*16 + g*4 + r;
            const bool z = mask[(gm & 3)*LIN_ + (gm >> 2)] != 0;
            #pragma unroll
            for (int nf = 0; nf < 4; ++nf) {
                float v = acc[mf][nf][r] + bv[nf];
                if (z) v = 0.f;
                C[(size_t)gm*256 + wc*64 + nf*16 + r16] = (unsigned short)bf16b(v);
            }
        }
    }
}

// ---------------- small GEMMs: bf16 MFMA, 64x64 tile, 4 waves ----------------
enum { EPI_NONE=0, EPI_RELU=1 };

template<int N, int K, int EPI>
__global__ __launch_bounds__(256)
void mfma_gemm_k(const float* __restrict__ A, const float* __restrict__ W,
                 const float* __restrict__ bias, float* __restrict__ C, int M)
{
    __shared__ __align__(16) short Al[64*64];
    __shared__ __align__(16) short Wl[64*64];

    const int tid  = threadIdx.x;
    const int lane = tid & 63;
    const int wid  = tid >> 6;
    const int wr   = wid >> 1;
    const int wc   = wid & 1;
    const int m0   = blockIdx.y * 64;
    const int n0   = blockIdx.x * 64;

    f32x4 acc[2][2];
    #pragma unroll
    for (int i = 0; i < 2; ++i)
        #pragma unroll
        for (int j = 0; j < 2; ++j) acc[i][j] = (f32x4){0.f,0.f,0.f,0.f};

    const int lr  = tid >> 4;
    const int lk4 = (tid & 15) * 4;

    for (int kt = 0; kt < K; kt += 64) {
        __syncthreads();
        #pragma unroll
        for (int sub = 0; sub < 4; ++sub) {
            const int r = lr + sub * 16;
            int gm = m0 + r; if (gm >= M) gm = M - 1;
            float4 v = *reinterpret_cast<const float4*>(&A[(size_t)gm*K + kt + lk4]);
            short4 s = { bf16b(v.x), bf16b(v.y), bf16b(v.z), bf16b(v.w) };
            *reinterpret_cast<short4*>((char*)Al + ((r*128 + lk4*2) ^ ((r & 7) << 4))) = s;
            const int n = n0 + r;
            float4 wv = *reinterpret_cast<const float4*>(&W[(size_t)n*K + kt + lk4]);
            short4 sw = { bf16b(wv.x), bf16b(wv.y), bf16b(wv.z), bf16b(wv.w) };
            *reinterpret_cast<short4*>((char*)Wl + ((r*128 + lk4*2) ^ ((r & 7) << 4))) = sw;
        }
        __syncthreads();
        #pragma unroll
        for (int kk = 0; kk < 2; ++kk) {
            const int kb = kk*64 + (lane >> 4) * 16;
            bh8 af[2], bf[2];
            #pragma unroll
            for (int mf = 0; mf < 2; ++mf) {
                const int row = wr*32 + mf*16 + (lane & 15);
                af[mf] = *reinterpret_cast<const bh8*>((char*)Al + ((row*128 + kb) ^ ((row & 7) << 4)));
            }
            #pragma unroll
            for (int nf = 0; nf < 2; ++nf) {
                const int col = wc*32 + nf*16 + (lane & 15);
                bf[nf] = *reinterpret_cast<const bh8*>((char*)Wl + ((col*128 + kb) ^ ((col & 7) << 4)));
            }
            #pragma unroll
            for (int mf = 0; mf < 2; ++mf)
                #pragma unroll
                for (int nf = 0; nf < 2; ++nf)
                    acc[mf][nf] = __builtin_amdgcn_mfma_f32_16x16x32_bf16(af[mf], bf[nf], acc[mf][nf], 0, 0, 0);
        }
    }

    float bv[2];
    #pragma unroll
    for (int nf = 0; nf < 2; ++nf) bv[nf] = bias[n0 + wc*32 + nf*16 + (lane & 15)];

    #pragma unroll
    for (int mf = 0; mf < 2; ++mf) {
        #pragma unroll
        for (int r = 0; r < 4; ++r) {
            const int m = m0 + wr*32 + mf*16 + (lane >> 4)*4 + r;
            if (m >= M) continue;
            #pragma unroll
            for (int nf = 0; nf < 2; ++nf) {
                float v = acc[mf][nf][r] + bv[nf];
                if (EPI == EPI_RELU) v = fmaxf(v, 0.f);
                C[(size_t)m*N + n0 + wc*32 + nf*16 + (lane & 15)] = v;
            }
        }
    }
}

// ---------------- deformable sampling ----------------
__global__ __launch_bounds__(256)
void msda_k(const float* __restrict__ off,
            const float* __restrict__ attnlog,
            const float* __restrict__ refp,
            const __hip_bfloat16* __restrict__ value,
            float* __restrict__ out)
{
    const int m = blockIdx.x;
    const int b = m & 3;
    const int d = threadIdx.x;
    const int h = d >> 5;

    __shared__ float s_off[256];
    __shared__ float s_al[128];
    __shared__ float s_ref[NL_*2];
    s_off[d] = off[(size_t)m*256 + d];
    if (d < 128) s_al[d] = attnlog[(size_t)m*128 + d];
    if (d < NL_*2) s_ref[d] = refp[(size_t)m*(NL_*2) + d];
    __syncthreads();

    float mx = -1e30f;
    #pragma unroll
    for (int t = 0; t < 16; ++t) mx = fmaxf(mx, s_al[h*16 + t]);
    float e[16], ssum = 0.f;
    #pragma unroll
    for (int t = 0; t < 16; ++t) { e[t] = __expf(s_al[h*16 + t] - mx); ssum += e[t]; }
    const float inv = 1.f / ssum;

    const int HS[4] = {128, 64, 32, 16};
    const int ST[4] = {0, 16384, 20480, 21504};

    float acc = 0.f;
    #pragma unroll
    for (int l = 0; l < NL_; ++l) {
        const int H = HS[l], W = HS[l], st = ST[l];
        const float rx = s_ref[l*2+0], ry = s_ref[l*2+1];
        #pragma unroll
        for (int p = 0; p < NP_; ++p) {
            const int base = ((h*NL_ + l)*NP_ + p);
            const float a  = e[l*4 + p] * inv;
            const float ox = s_off[base*2+0], oy = s_off[base*2+1];
            const float x = rx*(float)W + ox - 0.5f;
            const float y = ry*(float)H + oy - 0.5f;
            const float x0f = floorf(x), y0f = floorf(y);
            const int x0 = (int)x0f, y0 = (int)y0f;
            const float wx1 = x - x0f, wy1 = y - y0f;
            const float wx0 = 1.f - wx1, wy0 = 1.f - wy1;
            #pragma unroll
            for (int t = 0; t < 4; ++t) {
                const int xi = x0 + (t & 1);
                const int yi = y0 + (t >> 1);
                const float w = (t==0 ? wx0*wy0 : t==1 ? wx1*wy0 : t==2 ? wx0*wy1 : wx1*wy1);
                if (xi >= 0 && xi < W && yi >= 0 && yi < H) {
                    const size_t idx = (size_t)(st + yi*W + xi);
                    const float v = __bfloat162float(value[(idx*B_ + b)*D_ + d]);
                    acc = fmaf(a*w, v, acc);
                }
            }
        }
    }
    out[(size_t)m*256 + d] = acc;
}

// ---------------- fused add + LayerNorm ----------------
__global__ __launch_bounds__(256)
void add_ln_k(const float* __restrict__ x, const float* __restrict__ r,
              const float* __restrict__ g, const float* __restrict__ be,
              float* __restrict__ out)
{
    const int m = blockIdx.x, d = threadIdx.x;
    const float v = x[(size_t)m*D_ + d] + r[(size_t)m*D_ + d];
    float s1 = v, s2 = v*v;
    #pragma unroll
    for (int o = 32; o >= 1; o >>= 1) {
        s1 += __shfl_xor(s1, o, 64);
        s2 += __shfl_xor(s2, o, 64);
    }
    __shared__ float r1[4], r2[4];
    const int w = d >> 6;
    if ((d & 63) == 0) { r1[w] = s1; r2[w] = s2; }
    __syncthreads();
    const float t1 = r1[0]+r1[1]+r1[2]+r1[3];
    const float t2 = r2[0]+r2[1]+r2[2]+r2[3];
    const float mu  = t1 * (1.f/D_);
    const float var = t2 * (1.f/D_) - mu*mu;
    const float is  = rsqrtf(var + 1e-5f);
    out[(size_t)m*D_ + d] = (v - mu) * is * g[d] + be[d];
}

extern "C" void kernel_launch(void* const* d_in, const int* in_sizes, int n_in,
                              void* d_out, int out_size, void* d_ws, size_t ws_size,
                              hipStream_t stream)
{
    const float* tgt    = (const float*)d_in[0];
    const float* refp   = (const float*)d_in[1];
    const float* mem    = (const float*)d_in[2];
    const float* W_off  = (const float*)d_in[3];
    const float* b_off  = (const float*)d_in[4];
    const float* W_attn = (const float*)d_in[5];
    const float* b_attn = (const float*)d_in[6];
    const float* W_val  = (const float*)d_in[7];
    const float* b_val  = (const float*)d_in[8];
    const float* W_out  = (const float*)d_in[9];
    const float* b_out  = (const float*)d_in[10];
    const float* ln1g   = (const float*)d_in[11];
    const float* ln1b   = (const float*)d_in[12];
    const float* W1     = (const float*)d_in[13];
    const float* b1     = (const float*)d_in[14];
    const float* W2     = (const float*)d_in[15];
    const float* b2     = (const float*)d_in[16];
    const float* ln3g   = (const float*)d_in[17];
    const float* ln3b   = (const float*)d_in[18];
    const unsigned char* mask = (const unsigned char*)d_in[21];
    float* out = (float*)d_out;

    char* p = (char*)d_ws;
    __hip_bfloat16* value = (__hip_bfloat16*)p; p += (size_t)MV_*D_*2;
    float* offb = (float*)p; p += (size_t)MQ_*256*4;
    float* attl = (float*)p; p += (size_t)MQ_*128*4;
    float* msda = (float*)p; p += (size_t)MQ_*256*4;
    float* ca   = (float*)p; p += (size_t)MQ_*256*4;
    float* tb   = (float*)p; p += (size_t)MQ_*256*4;
    float* hb   = (float*)p; p += (size_t)MQ_*DFF_*4;
    float* yb   = (float*)p; p += (size_t)MQ_*256*4;
    unsigned char* wimg = (unsigned char*)p; p += 131072;
    (void)ws_size; (void)in_sizes; (void)n_in; (void)out_size;

    const int gy = (MQ_ + 63) / 64;   // 57

    // 0) W_val -> bf16 image
    wconv_k<<<dim3(64), dim3(256), 0, stream>>>(W_val, wimg);
    // 1) value = bf16(masked(memory @ W_val^T + b_val))  -- W-resident MFMA
    val_gemm_k<<<dim3(MV_/256), dim3(1024), 0, stream>>>(mem, wimg, b_val,
                                                         (unsigned short*)value, mask);
    // 2) off = tgt @ W_off^T + b_off
    mfma_gemm_k<256,256,EPI_NONE><<<dim3(4, gy), dim3(256), 0, stream>>>(tgt, W_off, b_off, offb, MQ_);
    // 3) attn logits
    mfma_gemm_k<128,256,EPI_NONE><<<dim3(2, gy), dim3(256), 0, stream>>>(tgt, W_attn, b_attn, attl, MQ_);
    // 4) deformable sampling
    msda_k<<<dim3(MQ_), dim3(256), 0, stream>>>(offb, attl, refp, value, msda);
    // 5) ca = msda @ W_out^T + b_out
    mfma_gemm_k<256,256,EPI_NONE><<<dim3(4, gy), dim3(256), 0, stream>>>(msda, W_out, b_out, ca, MQ_);
    // 6) t = LN(tgt + ca)
    add_ln_k<<<dim3(MQ_), dim3(256), 0, stream>>>(ca, tgt, ln1g, ln1b, tb);
    // 7) h = relu(t @ W1^T + b1)
    mfma_gemm_k<DFF_,256,EPI_RELU><<<dim3(16, gy), dim3(256), 0, stream>>>(tb, W1, b1, hb, MQ_);
    // 8) y = h @ W2^T + b2
    mfma_gemm_k<256,DFF_,EPI_NONE><<<dim3(4, gy), dim3(256), 0, stream>>>(hb, W2, b2, yb, MQ_);
    // 9) out = LN(t + y)
    add_ln_k<<<dim3(MQ_), dim3(256), 0, stream>>>(yb, tb, ln3g, ln3b, out);
}

// Round 6
// 201.307 us; speedup vs baseline: 1.1495x; 1.1495x over previous
//
#include <hip/hip_runtime.h>
#include <hip/hip_bf16.h>

#define B_   4
#define LQ_  900
#define D_   256
#define NH_  8
#define DH_  32
#define NL_  4
#define NP_  4
#define DFF_ 1024
#define LIN_ 21760
#define MQ_  (LQ_*B_)    // 3600
#define MV_  (LIN_*B_)   // 87040

typedef __attribute__((ext_vector_type(8))) short bh8;
typedef __attribute__((ext_vector_type(4))) float f32x4;

__device__ __forceinline__ short bf16b(float f) {
    __hip_bfloat16 h = __float2bfloat16(f);
    return *reinterpret_cast<short*>(&h);
}

__device__ __forceinline__ void gload_lds16(const void* g, void* l) {
    __builtin_amdgcn_global_load_lds(
        (const __attribute__((address_space(1))) unsigned int*)g,
        (__attribute__((address_space(3))) unsigned int*)l, 16, 0, 0);
}

// ---- W_val -> bf16 image: 4 k-chunks of 32 KB, rows XOR-swizzled ----
__global__ __launch_bounds__(256)
void wconv_k(const float* __restrict__ W, unsigned char* __restrict__ img)
{
    const int idx = blockIdx.x*256 + threadIdx.x;   // 16384 threads
    const int n  = idx >> 6;
    const int k0 = (idx & 63) * 4;
    const int kt = k0 >> 6;
    const int k2 = k0 & 63;
    float4 v = *reinterpret_cast<const float4*>(&W[(size_t)n*256 + k0]);
    short4 s = { bf16b(v.x), bf16b(v.y), bf16b(v.z), bf16b(v.w) };
    const int off = kt*32768 + ((n*128 + k2*2) ^ ((n & 7) << 4));
    *reinterpret_cast<short4*>(img + off) = s;
}

// ---- memory fp32 -> bf16 pre-swizzled tile image ----
// layout: tile T (128 rows) x k-chunk kt (64 cols) = 16 KB blocks;
// within: byte ((r*128 + k2*2) ^ ((r&7)<<4))  -- matches val_gemm's ds_read swizzle
__global__ __launch_bounds__(256)
void aconv_k(const float* __restrict__ A, unsigned char* __restrict__ img)
{
    const size_t lin = ((size_t)blockIdx.x*256 + threadIdx.x) * 8;   // 8 elems/thread
    const int m  = (int)(lin >> 8);
    const int k0 = (int)(lin & 255);
    float4 v0 = *reinterpret_cast<const float4*>(&A[(size_t)m*256 + k0]);
    float4 v1 = *reinterpret_cast<const float4*>(&A[(size_t)m*256 + k0 + 4]);
    union { short s[8]; uint4 v; } pk;
    pk.s[0]=bf16b(v0.x); pk.s[1]=bf16b(v0.y); pk.s[2]=bf16b(v0.z); pk.s[3]=bf16b(v0.w);
    pk.s[4]=bf16b(v1.x); pk.s[5]=bf16b(v1.y); pk.s[6]=bf16b(v1.z); pk.s[7]=bf16b(v1.w);
    const int r  = m & 127;
    const size_t off = (size_t)(m >> 7)*65536 + (size_t)(k0 >> 6)*16384
                     + (((r*128) + (k0 & 63)*2) ^ ((r & 7) << 4));
    *reinterpret_cast<uint4*>(img + off) = pk.v;
}

// ---------------- value GEMM: pure bf16, m97 2-barrier pattern ----------------
// 128x256 tile, BK=64, 512 threads (8 waves 2x4), LDS 48 KB -> 3 blocks/CU
__global__ __launch_bounds__(512)
void val_gemm_k(const unsigned char* __restrict__ Aimg, const unsigned char* __restrict__ Wimg,
                const float* __restrict__ bias, unsigned short* __restrict__ C,
                const unsigned char* __restrict__ mask)
{
    __shared__ __align__(16) unsigned char Al[16384];
    __shared__ __align__(16) unsigned char Wl[32768];

    const int tid  = threadIdx.x;
    const int lane = tid & 63;
    const int wid  = tid >> 6;     // 0..7
    const int wr   = wid >> 2;     // 0..1
    const int wc   = wid & 3;      // 0..3
    const int m0   = blockIdx.x * 128;
    const int r16  = lane & 15;
    const int g    = lane >> 4;    // 0..3

    const unsigned char* Abase = Aimg + (size_t)blockIdx.x * 65536;

    f32x4 acc[4][4];
    #pragma unroll
    for (int i = 0; i < 4; ++i)
        #pragma unroll
        for (int j = 0; j < 4; ++j) acc[i][j] = (f32x4){0.f,0.f,0.f,0.f};

    for (int kt = 0; kt < 4; ++kt) {
        __syncthreads();   // previous compute's LDS readers done
        {
            const unsigned char* asrc = Abase + kt*16384 + wid*2048 + lane*16;
            char* adst = (char*)Al + wid*2048 + lane*16;
            gload_lds16(asrc,        adst);
            gload_lds16(asrc + 1024, adst + 1024);
            const unsigned char* wsrc = Wimg + kt*32768 + wid*4096 + lane*16;
            char* wdst = (char*)Wl + wid*4096 + lane*16;
            #pragma unroll
            for (int j = 0; j < 4; ++j) gload_lds16(wsrc + j*1024, wdst + j*1024);
        }
        __syncthreads();   // vmcnt(0) drain -> tiles resident
        #pragma unroll
        for (int kk = 0; kk < 2; ++kk) {
            const int kb = kk*64 + g*16;
            bh8 af[4], bf[4];
            #pragma unroll
            for (int mf = 0; mf < 4; ++mf) {
                const int row = wr*64 + mf*16 + r16;
                af[mf] = *reinterpret_cast<const bh8*>(Al + ((row*128 + kb) ^ ((row & 7) << 4)));
            }
            #pragma unroll
            for (int nf = 0; nf < 4; ++nf) {
                const int col = wc*64 + nf*16 + r16;
                bf[nf] = *reinterpret_cast<const bh8*>(Wl + ((col*128 + kb) ^ ((col & 7) << 4)));
            }
            #pragma unroll
            for (int mf = 0; mf < 4; ++mf)
                #pragma unroll
                for (int nf = 0; nf < 4; ++nf)
                    acc[mf][nf] = __builtin_amdgcn_mfma_f32_16x16x32_bf16(af[mf], bf[nf], acc[mf][nf], 0, 0, 0);
        }
    }

    float bv[4];
    #pragma unroll
    for (int nf = 0; nf < 4; ++nf) bv[nf] = bias[wc*64 + nf*16 + r16];

    #pragma unroll
    for (int mf = 0; mf < 4; ++mf) {
        #pragma unroll
        for (int r = 0; r < 4; ++r) {
            const int gm = m0 + wr*64 + mf*16 + g*4 + r;
            const bool z = mask[(gm & 3)*LIN_ + (gm >> 2)] != 0;
            #pragma unroll
            for (int nf = 0; nf < 4; ++nf) {
                float v = acc[mf][nf][r] + bv[nf];
                if (z) v = 0.f;
                C[(size_t)gm*256 + wc*64 + nf*16 + r16] = (unsigned short)bf16b(v);
            }
        }
    }
}

// ---------------- small GEMMs: bf16 MFMA, 64x64 tile, 4 waves ----------------
enum { EPI_NONE=0, EPI_RELU=1 };

template<int N, int K, int EPI>
__global__ __launch_bounds__(256)
void mfma_gemm_k(const float* __restrict__ A, const float* __restrict__ W,
                 const float* __restrict__ bias, float* __restrict__ C, int M)
{
    __shared__ __align__(16) short Al[64*64];
    __shared__ __align__(16) short Wl[64*64];

    const int tid  = threadIdx.x;
    const int lane = tid & 63;
    const int wid  = tid >> 6;
    const int wr   = wid >> 1;
    const int wc   = wid & 1;
    const int m0   = blockIdx.y * 64;
    const int n0   = blockIdx.x * 64;

    f32x4 acc[2][2];
    #pragma unroll
    for (int i = 0; i < 2; ++i)
        #pragma unroll
        for (int j = 0; j < 2; ++j) acc[i][j] = (f32x4){0.f,0.f,0.f,0.f};

    const int lr  = tid >> 4;
    const int lk4 = (tid & 15) * 4;

    for (int kt = 0; kt < K; kt += 64) {
        __syncthreads();
        #pragma unroll
        for (int sub = 0; sub < 4; ++sub) {
            const int r = lr + sub * 16;
            int gm = m0 + r; if (gm >= M) gm = M - 1;
            float4 v = *reinterpret_cast<const float4*>(&A[(size_t)gm*K + kt + lk4]);
            short4 s = { bf16b(v.x), bf16b(v.y), bf16b(v.z), bf16b(v.w) };
            *reinterpret_cast<short4*>((char*)Al + ((r*128 + lk4*2) ^ ((r & 7) << 4))) = s;
            const int n = n0 + r;
            float4 wv = *reinterpret_cast<const float4*>(&W[(size_t)n*K + kt + lk4]);
            short4 sw = { bf16b(wv.x), bf16b(wv.y), bf16b(wv.z), bf16b(wv.w) };
            *reinterpret_cast<short4*>((char*)Wl + ((r*128 + lk4*2) ^ ((r & 7) << 4))) = sw;
        }
        __syncthreads();
        #pragma unroll
        for (int kk = 0; kk < 2; ++kk) {
            const int kb = kk*64 + (lane >> 4) * 16;
            bh8 af[2], bf[2];
            #pragma unroll
            for (int mf = 0; mf < 2; ++mf) {
                const int row = wr*32 + mf*16 + (lane & 15);
                af[mf] = *reinterpret_cast<const bh8*>((char*)Al + ((row*128 + kb) ^ ((row & 7) << 4)));
            }
            #pragma unroll
            for (int nf = 0; nf < 2; ++nf) {
                const int col = wc*32 + nf*16 + (lane & 15);
                bf[nf] = *reinterpret_cast<const bh8*>((char*)Wl + ((col*128 + kb) ^ ((col & 7) << 4)));
            }
            #pragma unroll
            for (int mf = 0; mf < 2; ++mf)
                #pragma unroll
                for (int nf = 0; nf < 2; ++nf)
                    acc[mf][nf] = __builtin_amdgcn_mfma_f32_16x16x32_bf16(af[mf], bf[nf], acc[mf][nf], 0, 0, 0);
        }
    }

    float bv[2];
    #pragma unroll
    for (int nf = 0; nf < 2; ++nf) bv[nf] = bias[n0 + wc*32 + nf*16 + (lane & 15)];

    #pragma unroll
    for (int mf = 0; mf < 2; ++mf) {
        #pragma unroll
        for (int r = 0; r < 4; ++r) {
            const int m = m0 + wr*32 + mf*16 + (lane >> 4)*4 + r;
            if (m >= M) continue;
            #pragma unroll
            for (int nf = 0; nf < 2; ++nf) {
                float v = acc[mf][nf][r] + bv[nf];
                if (EPI == EPI_RELU) v = fmaxf(v, 0.f);
                C[(size_t)m*N + n0 + wc*32 + nf*16 + (lane & 15)] = v;
            }
        }
    }
}

// ---------------- deformable sampling ----------------
__global__ __launch_bounds__(256)
void msda_k(const float* __restrict__ off,
            const float* __restrict__ attnlog,
            const float* __restrict__ refp,
            const __hip_bfloat16* __restrict__ value,
            float* __restrict__ out)
{
    const int m = blockIdx.x;
    const int b = m & 3;
    const int d = threadIdx.x;
    const int h = d >> 5;

    __shared__ float s_off[256];
    __shared__ float s_al[128];
    __shared__ float s_ref[NL_*2];
    s_off[d] = off[(size_t)m*256 + d];
    if (d < 128) s_al[d] = attnlog[(size_t)m*128 + d];
    if (d < NL_*2) s_ref[d] = refp[(size_t)m*(NL_*2) + d];
    __syncthreads();

    float mx = -1e30f;
    #pragma unroll
    for (int t = 0; t < 16; ++t) mx = fmaxf(mx, s_al[h*16 + t]);
    float e[16], ssum = 0.f;
    #pragma unroll
    for (int t = 0; t < 16; ++t) { e[t] = __expf(s_al[h*16 + t] - mx); ssum += e[t]; }
    const float inv = 1.f / ssum;

    const int HS[4] = {128, 64, 32, 16};
    const int ST[4] = {0, 16384, 20480, 21504};

    float acc = 0.f;
    #pragma unroll
    for (int l = 0; l < NL_; ++l) {
        const int H = HS[l], W = HS[l], st = ST[l];
        const float rx = s_ref[l*2+0], ry = s_ref[l*2+1];
        #pragma unroll
        for (int p = 0; p < NP_; ++p) {
            const int base = ((h*NL_ + l)*NP_ + p);
            const float a  = e[l*4 + p] * inv;
            const float ox = s_off[base*2+0], oy = s_off[base*2+1];
            const float x = rx*(float)W + ox - 0.5f;
            const float y = ry*(float)H + oy - 0.5f;
            const float x0f = floorf(x), y0f = floorf(y);
            const int x0 = (int)x0f, y0 = (int)y0f;
            const float wx1 = x - x0f, wy1 = y - y0f;
            const float wx0 = 1.f - wx1, wy0 = 1.f - wy1;
            #pragma unroll
            for (int t = 0; t < 4; ++t) {
                const int xi = x0 + (t & 1);
                const int yi = y0 + (t >> 1);
                const float w = (t==0 ? wx0*wy0 : t==1 ? wx1*wy0 : t==2 ? wx0*wy1 : wx1*wy1);
                if (xi >= 0 && xi < W && yi >= 0 && yi < H) {
                    const size_t idx = (size_t)(st + yi*W + xi);
                    const float v = __bfloat162float(value[(idx*B_ + b)*D_ + d]);
                    acc = fmaf(a*w, v, acc);
                }
            }
        }
    }
    out[(size_t)m*256 + d] = acc;
}

// ---------------- fused add + LayerNorm ----------------
__global__ __launch_bounds__(256)
void add_ln_k(const float* __restrict__ x, const float* __restrict__ r,
              const float* __restrict__ g, const float* __restrict__ be,
              float* __restrict__ out)
{
    const int m = blockIdx.x, d = threadIdx.x;
    const float v = x[(size_t)m*D_ + d] + r[(size_t)m*D_ + d];
    float s1 = v, s2 = v*v;
    #pragma unroll
    for (int o = 32; o >= 1; o >>= 1) {
        s1 += __shfl_xor(s1, o, 64);
        s2 += __shfl_xor(s2, o, 64);
    }
    __shared__ float r1[4], r2[4];
    const int w = d >> 6;
    if ((d & 63) == 0) { r1[w] = s1; r2[w] = s2; }
    __syncthreads();
    const float t1 = r1[0]+r1[1]+r1[2]+r1[3];
    const float t2 = r2[0]+r2[1]+r2[2]+r2[3];
    const float mu  = t1 * (1.f/D_);
    const float var = t2 * (1.f/D_) - mu*mu;
    const float is  = rsqrtf(var + 1e-5f);
    out[(size_t)m*D_ + d] = (v - mu) * is * g[d] + be[d];
}

extern "C" void kernel_launch(void* const* d_in, const int* in_sizes, int n_in,
                              void* d_out, int out_size, void* d_ws, size_t ws_size,
                              hipStream_t stream)
{
    const float* tgt    = (const float*)d_in[0];
    const float* refp   = (const float*)d_in[1];
    const float* mem    = (const float*)d_in[2];
    const float* W_off  = (const float*)d_in[3];
    const float* b_off  = (const float*)d_in[4];
    const float* W_attn = (const float*)d_in[5];
    const float* b_attn = (const float*)d_in[6];
    const float* W_val  = (const float*)d_in[7];
    const float* b_val  = (const float*)d_in[8];
    const float* W_out  = (const float*)d_in[9];
    const float* b_out  = (const float*)d_in[10];
    const float* ln1g   = (const float*)d_in[11];
    const float* ln1b   = (const float*)d_in[12];
    const float* W1     = (const float*)d_in[13];
    const float* b1     = (const float*)d_in[14];
    const float* W2     = (const float*)d_in[15];
    const float* b2     = (const float*)d_in[16];
    const float* ln3g   = (const float*)d_in[17];
    const float* ln3b   = (const float*)d_in[18];
    const unsigned char* mask = (const unsigned char*)d_in[21];
    float* out = (float*)d_out;

    char* p = (char*)d_ws;
    __hip_bfloat16* value = (__hip_bfloat16*)p; p += (size_t)MV_*D_*2;   // 44.6 MB (aliases A-image)
    float* offb = (float*)p; p += (size_t)MQ_*256*4;
    float* attl = (float*)p; p += (size_t)MQ_*128*4;
    float* msda = (float*)p; p += (size_t)MQ_*256*4;
    float* ca   = (float*)p; p += (size_t)MQ_*256*4;
    float* tb   = (float*)p; p += (size_t)MQ_*256*4;
    float* hb   = (float*)p; p += (size_t)MQ_*DFF_*4;
    float* yb   = (float*)p; p += (size_t)MQ_*256*4;
    unsigned char* wimg = (unsigned char*)p; p += 131072;
    (void)ws_size; (void)in_sizes; (void)n_in; (void)out_size;

    unsigned char* aimg = (unsigned char*)value;   // in-place: block T reads A-image window T,
                                                   // then (after all reads) writes value rows into the same window
    const int gy = (MQ_ + 63) / 64;   // 57

    // 0) weight + activation images (bf16, pre-swizzled)
    wconv_k<<<dim3(64), dim3(256), 0, stream>>>(W_val, wimg);
    aconv_k<<<dim3((MV_*256/8)/256), dim3(256), 0, stream>>>(mem, aimg);
    // 1) value = bf16(masked(A @ W_val^T + b_val))  -- pure-bf16 m97-pattern MFMA
    val_gemm_k<<<dim3(MV_/128), dim3(512), 0, stream>>>(aimg, wimg, b_val,
                                                        (unsigned short*)value, mask);
    // 2) off = tgt @ W_off^T + b_off
    mfma_gemm_k<256,256,EPI_NONE><<<dim3(4, gy), dim3(256), 0, stream>>>(tgt, W_off, b_off, offb, MQ_);
    // 3) attn logits
    mfma_gemm_k<128,256,EPI_NONE><<<dim3(2, gy), dim3(256), 0, stream>>>(tgt, W_attn, b_attn, attl, MQ_);
    // 4) deformable sampling
    msda_k<<<dim3(MQ_), dim3(256), 0, stream>>>(offb, attl, refp, value, msda);
    // 5) ca = msda @ W_out^T + b_out
    mfma_gemm_k<256,256,EPI_NONE><<<dim3(4, gy), dim3(256), 0, stream>>>(msda, W_out, b_out, ca, MQ_);
    // 6) t = LN(tgt + ca)
    add_ln_k<<<dim3(MQ_), dim3(256), 0, stream>>>(ca, tgt, ln1g, ln1b, tb);
    // 7) h = relu(t @ W1^T + b1)
    mfma_gemm_k<DFF_,256,EPI_RELU><<<dim3(16, gy), dim3(256), 0, stream>>>(tb, W1, b1, hb, MQ_);
    // 8) y = h @ W2^T + b2
    mfma_gemm_k<256,DFF_,EPI_NONE><<<dim3(4, gy), dim3(256), 0, stream>>>(hb, W2, b2, yb, MQ_);
    // 9) out = LN(t + y)
    add_ln_k<<<dim3(MQ_), dim3(256), 0, stream>>>(yb, tb, ln3g, ln3b, out);
}

// Round 7
// 146.292 us; speedup vs baseline: 1.5818x; 1.3761x over previous
//
#include <hip/hip_runtime.h>
#include <hip/hip_bf16.h>

#define B_   4
#define LQ_  900
#define D_   256
#define NH_  8
#define DH_  32
#define NL_  4
#define NP_  4
#define DFF_ 1024
#define LIN_ 21760
#define MQ_  (LQ_*B_)    // 3600
#define MV_  (LIN_*B_)   // 87040

typedef __attribute__((ext_vector_type(8))) short bh8;
typedef __attribute__((ext_vector_type(4))) float f32x4;

__device__ __forceinline__ short bf16b(float f) {
    __hip_bfloat16 h = __float2bfloat16(f);
    return *reinterpret_cast<short*>(&h);
}

__device__ __forceinline__ void gload_lds16(const void* g, void* l) {
    __builtin_amdgcn_global_load_lds(
        (const __attribute__((address_space(1))) unsigned int*)g,
        (__attribute__((address_space(3))) unsigned int*)l, 16, 0, 0);
}

__device__ __forceinline__ bh8 af_from_f32(const float* p) {
    float4 v0 = *reinterpret_cast<const float4*>(p);
    float4 v1 = *reinterpret_cast<const float4*>(p + 4);
    return (bh8){ bf16b(v0.x), bf16b(v0.y), bf16b(v0.z), bf16b(v0.w),
                  bf16b(v1.x), bf16b(v1.y), bf16b(v1.z), bf16b(v1.w) };
}

// ---- W_val -> bf16 image for val_gemm (swizzled LDS-image, unchanged) ----
__global__ __launch_bounds__(256)
void wconv_k(const float* __restrict__ W, unsigned char* __restrict__ img)
{
    const int idx = blockIdx.x*256 + threadIdx.x;
    const int n  = idx >> 6;
    const int k0 = (idx & 63) * 4;
    const int kt = k0 >> 6;
    const int k2 = k0 & 63;
    float4 v = *reinterpret_cast<const float4*>(&W[(size_t)n*256 + k0]);
    short4 s = { bf16b(v.x), bf16b(v.y), bf16b(v.z), bf16b(v.w) };
    const int off = kt*32768 + ((n*128 + k2*2) ^ ((n & 7) << 4));
    *reinterpret_cast<short4*>(img + off) = s;
}

// ---- all other weights -> MFMA B-frag images ----
// image block (ntile, kq of 32): 1 KB; byte (g*16+n16)*16 + j*2 = W[ntile*16+n16][kq*32+g*8+j]
__global__ __launch_bounds__(256)
void wprep_k(const float* __restrict__ Woff, const float* __restrict__ Wattn,
             const float* __restrict__ Wout, const float* __restrict__ W1,
             const float* __restrict__ W2,
             unsigned char* __restrict__ qkvimg, unsigned char* __restrict__ outimg,
             unsigned char* __restrict__ w1img, unsigned char* __restrict__ w2img)
{
    const int cid = blockIdx.x*256 + threadIdx.x;   // 86016 total
    const float* W; unsigned char* img; int KQ, c;
    if      (cid < 8192)  { W=Woff;  img=qkvimg;           KQ=8;  c=cid;       }
    else if (cid < 12288) { W=Wattn; img=qkvimg + 131072;  KQ=8;  c=cid-8192;  }
    else if (cid < 20480) { W=Wout;  img=outimg;           KQ=8;  c=cid-12288; }
    else if (cid < 53248) { W=W1;    img=w1img;            KQ=8;  c=cid-20480; }
    else                  { W=W2;    img=w2img;            KQ=32; c=cid-53248; }
    const int K   = KQ*32;
    const int n16 = c & 15, g = (c>>4)&3, t = c>>6;
    const int kq  = t & (KQ-1);
    const int ntile = t >> ((KQ==8) ? 3 : 5);
    const int n = ntile*16 + n16, k0 = kq*32 + g*8;
    float4 v0 = *reinterpret_cast<const float4*>(&W[(size_t)n*K + k0]);
    float4 v1 = *reinterpret_cast<const float4*>(&W[(size_t)n*K + k0 + 4]);
    union { short s[8]; uint4 u; } pk;
    pk.s[0]=bf16b(v0.x); pk.s[1]=bf16b(v0.y); pk.s[2]=bf16b(v0.z); pk.s[3]=bf16b(v0.w);
    pk.s[4]=bf16b(v1.x); pk.s[5]=bf16b(v1.y); pk.s[6]=bf16b(v1.z); pk.s[7]=bf16b(v1.w);
    *reinterpret_cast<uint4*>(img + (size_t)(ntile*KQ + kq)*1024 + (g*16+n16)*16) = pk.u;
}

// ---- memory fp32 -> bf16 pre-swizzled tile image (val_gemm A side) ----
__global__ __launch_bounds__(256)
void aconv_k(const float* __restrict__ A, unsigned char* __restrict__ img)
{
    const size_t lin = ((size_t)blockIdx.x*256 + threadIdx.x) * 8;
    const int m  = (int)(lin >> 8);
    const int k0 = (int)(lin & 255);
    float4 v0 = *reinterpret_cast<const float4*>(&A[(size_t)m*256 + k0]);
    float4 v1 = *reinterpret_cast<const float4*>(&A[(size_t)m*256 + k0 + 4]);
    union { short s[8]; uint4 v; } pk;
    pk.s[0]=bf16b(v0.x); pk.s[1]=bf16b(v0.y); pk.s[2]=bf16b(v0.z); pk.s[3]=bf16b(v0.w);
    pk.s[4]=bf16b(v1.x); pk.s[5]=bf16b(v1.y); pk.s[6]=bf16b(v1.z); pk.s[7]=bf16b(v1.w);
    const int r  = m & 127;
    const size_t off = (size_t)(m >> 7)*65536 + (size_t)(k0 >> 6)*16384
                     + (((r*128) + (k0 & 63)*2) ^ ((r & 7) << 4));
    *reinterpret_cast<uint4*>(img + off) = pk.v;
}

// ---------------- value GEMM: pure bf16, m97 2-barrier pattern (R6, 65->good) ----------------
__global__ __launch_bounds__(512)
void val_gemm_k(const unsigned char* __restrict__ Aimg, const unsigned char* __restrict__ Wimg,
                const float* __restrict__ bias, unsigned short* __restrict__ C,
                const unsigned char* __restrict__ mask)
{
    __shared__ __align__(16) unsigned char Al[16384];
    __shared__ __align__(16) unsigned char Wl[32768];

    const int tid  = threadIdx.x;
    const int lane = tid & 63;
    const int wid  = tid >> 6;
    const int wr   = wid >> 2;
    const int wc   = wid & 3;
    const int m0   = blockIdx.x * 128;
    const int r16  = lane & 15;
    const int g    = lane >> 4;

    const unsigned char* Abase = Aimg + (size_t)blockIdx.x * 65536;

    f32x4 acc[4][4];
    #pragma unroll
    for (int i = 0; i < 4; ++i)
        #pragma unroll
        for (int j = 0; j < 4; ++j) acc[i][j] = (f32x4){0.f,0.f,0.f,0.f};

    for (int kt = 0; kt < 4; ++kt) {
        __syncthreads();
        {
            const unsigned char* asrc = Abase + kt*16384 + wid*2048 + lane*16;
            char* adst = (char*)Al + wid*2048 + lane*16;
            gload_lds16(asrc,        adst);
            gload_lds16(asrc + 1024, adst + 1024);
            const unsigned char* wsrc = Wimg + kt*32768 + wid*4096 + lane*16;
            char* wdst = (char*)Wl + wid*4096 + lane*16;
            #pragma unroll
            for (int j = 0; j < 4; ++j) gload_lds16(wsrc + j*1024, wdst + j*1024);
        }
        __syncthreads();
        #pragma unroll
        for (int kk = 0; kk < 2; ++kk) {
            const int kb = kk*64 + g*16;
            bh8 af[4], bf[4];
            #pragma unroll
            for (int mf = 0; mf < 4; ++mf) {
                const int row = wr*64 + mf*16 + r16;
                af[mf] = *reinterpret_cast<const bh8*>(Al + ((row*128 + kb) ^ ((row & 7) << 4)));
            }
            #pragma unroll
            for (int nf = 0; nf < 4; ++nf) {
                const int col = wc*64 + nf*16 + r16;
                bf[nf] = *reinterpret_cast<const bh8*>(Wl + ((col*128 + kb) ^ ((col & 7) << 4)));
            }
            #pragma unroll
            for (int mf = 0; mf < 4; ++mf)
                #pragma unroll
                for (int nf = 0; nf < 4; ++nf)
                    acc[mf][nf] = __builtin_amdgcn_mfma_f32_16x16x32_bf16(af[mf], bf[nf], acc[mf][nf], 0, 0, 0);
        }
    }

    float bv[4];
    #pragma unroll
    for (int nf = 0; nf < 4; ++nf) bv[nf] = bias[wc*64 + nf*16 + r16];

    #pragma unroll
    for (int mf = 0; mf < 4; ++mf) {
        #pragma unroll
        for (int r = 0; r < 4; ++r) {
            const int gm = m0 + wr*64 + mf*16 + g*4 + r;
            const bool z = mask[(gm & 3)*LIN_ + (gm >> 2)] != 0;
            #pragma unroll
            for (int nf = 0; nf < 4; ++nf) {
                float v = acc[mf][nf][r] + bv[nf];
                if (z) v = 0.f;
                C[(size_t)gm*256 + wc*64 + nf*16 + r16] = (unsigned short)bf16b(v);
            }
        }
    }
}

// ---------------- fused off+attn projections: A-frags from global, weight images ----------------
// M-tile 16 (block-private rows -> no cross-XCD A refetch), 512 thr, 24 n-tiles (256 off + 128 attn)
__global__ __launch_bounds__(512)
void qkv_k(const float* __restrict__ A, const unsigned char* __restrict__ Wimg,
           const float* __restrict__ b_off, const float* __restrict__ b_attn,
           float* __restrict__ Yoff, float* __restrict__ Yattn)
{
    const int tid = threadIdx.x, lane = tid & 63, w = tid >> 6;
    const int m16 = lane & 15, g = lane >> 4;
    const int m0 = blockIdx.x * 16;

    bh8 af[8];
    #pragma unroll
    for (int kq = 0; kq < 8; ++kq)
        af[kq] = af_from_f32(&A[(size_t)(m0 + m16)*256 + kq*32 + g*8]);

    f32x4 acc[3];
    #pragma unroll
    for (int i = 0; i < 3; ++i) acc[i] = (f32x4){0.f,0.f,0.f,0.f};

    #pragma unroll
    for (int i = 0; i < 3; ++i) {
        const int nt = w*3 + i;
        #pragma unroll
        for (int kq = 0; kq < 8; ++kq) {
            bh8 bf = *reinterpret_cast<const bh8*>(Wimg + (size_t)(nt*8 + kq)*1024 + lane*16);
            acc[i] = __builtin_amdgcn_mfma_f32_16x16x32_bf16(af[kq], bf, acc[i], 0, 0, 0);
        }
    }

    #pragma unroll
    for (int i = 0; i < 3; ++i) {
        const int nt = w*3 + i;
        const int j  = nt*16 + m16;
        #pragma unroll
        for (int r = 0; r < 4; ++r) {
            const int m = m0 + g*4 + r;
            if (nt < 16) Yoff[(size_t)m*256 + j] = acc[i][r] + b_off[j];
            else         Yattn[(size_t)m*128 + (j-256)] = acc[i][r] + b_attn[j-256];
        }
    }
}

// ---------------- out projection (step 5), same structure, N=256 ----------------
__global__ __launch_bounds__(512)
void out_k(const float* __restrict__ A, const unsigned char* __restrict__ Wimg,
           const float* __restrict__ bias, float* __restrict__ Y)
{
    const int tid = threadIdx.x, lane = tid & 63, w = tid >> 6;
    const int m16 = lane & 15, g = lane >> 4;
    const int m0 = blockIdx.x * 16;

    bh8 af[8];
    #pragma unroll
    for (int kq = 0; kq < 8; ++kq)
        af[kq] = af_from_f32(&A[(size_t)(m0 + m16)*256 + kq*32 + g*8]);

    f32x4 acc[2];
    acc[0] = (f32x4){0.f,0.f,0.f,0.f};
    acc[1] = (f32x4){0.f,0.f,0.f,0.f};

    #pragma unroll
    for (int i = 0; i < 2; ++i) {
        const int nt = w*2 + i;
        #pragma unroll
        for (int kq = 0; kq < 8; ++kq) {
            bh8 bf = *reinterpret_cast<const bh8*>(Wimg + (size_t)(nt*8 + kq)*1024 + lane*16);
            acc[i] = __builtin_amdgcn_mfma_f32_16x16x32_bf16(af[kq], bf, acc[i], 0, 0, 0);
        }
    }

    #pragma unroll
    for (int i = 0; i < 2; ++i) {
        const int nt = w*2 + i;
        const int j  = nt*16 + m16;
        #pragma unroll
        for (int r = 0; r < 4; ++r) {
            const int m = m0 + g*4 + r;
            Y[(size_t)m*256 + j] = acc[i][r] + bias[j];
        }
    }
}

// ---------------- fused FFN: y_partial[fg] = relu(t@W1^T+b1)[:,fg] @ W2[:,fg]^T ----------------
// M-tile 32, f-split 4 (grid 113x4), 512 thr / 8 waves; h lives only in 9 KB LDS (dbuf)
__global__ __launch_bounds__(512)
void ffn_k(const float* __restrict__ T, const unsigned char* __restrict__ W1img,
           const float* __restrict__ b1, const unsigned char* __restrict__ W2img,
           const float* __restrict__ b2, float* __restrict__ Y)
{
    __shared__ __align__(16) short hl[2][32*72];   // [32 m][72 f(64+pad)] bf16, dbuf

    const int tid = threadIdx.x, lane = tid & 63, w = tid >> 6;
    const int m16 = lane & 15, g = lane >> 4;
    const int mt = w & 1, wn = w >> 1;             // stage1: ft=wn; stage2: nt=wn*4+i
    const int m0 = blockIdx.x * 32;
    const int fg = blockIdx.y;

    bh8 af1[8];
    #pragma unroll
    for (int kq = 0; kq < 8; ++kq) {
        int gm = m0 + mt*16 + m16; if (gm > MQ_-1) gm = MQ_-1;
        af1[kq] = af_from_f32(&T[(size_t)gm*256 + kq*32 + g*8]);
    }

    f32x4 yacc[4];
    #pragma unroll
    for (int i = 0; i < 4; ++i) yacc[i] = (f32x4){0.f,0.f,0.f,0.f};

    int buf = 0;
    #pragma unroll
    for (int fc = 0; fc < 4; ++fc) {
        const int ftile_g = fg*16 + fc*4 + wn;          // global f-tile for stage1
        // stage1: one h-frag per wave
        f32x4 hacc = (f32x4){0.f,0.f,0.f,0.f};
        #pragma unroll
        for (int kq = 0; kq < 8; ++kq) {
            bh8 bf = *reinterpret_cast<const bh8*>(W1img + (size_t)(ftile_g*8 + kq)*1024 + lane*16);
            hacc = __builtin_amdgcn_mfma_f32_16x16x32_bf16(af1[kq], bf, hacc, 0, 0, 0);
        }
        const float bb = b1[ftile_g*16 + m16];
        #pragma unroll
        for (int r = 0; r < 4; ++r) {
            const float v = fmaxf(hacc[r] + bb, 0.f);
            *reinterpret_cast<short*>((char*)&hl[buf][0]
                + (mt*16 + g*4 + r)*144 + (wn*16 + m16)*2) = bf16b(v);
        }
        __syncthreads();   // publish h chunk (dbuf -> single barrier per chunk)
        // stage2: 4 y-frags per wave
        bh8 a2[2];
        #pragma unroll
        for (int kqf = 0; kqf < 2; ++kqf)
            a2[kqf] = *reinterpret_cast<const bh8*>((char*)&hl[buf][0]
                + (mt*16 + m16)*144 + (kqf*32 + g*8)*2);
        #pragma unroll
        for (int i = 0; i < 4; ++i) {
            const int nt = wn*4 + i;
            #pragma unroll
            for (int kqf = 0; kqf < 2; ++kqf) {
                const int kq2 = fg*8 + fc*2 + kqf;
                bh8 bf = *reinterpret_cast<const bh8*>(W2img + (size_t)(nt*32 + kq2)*1024 + lane*16);
                yacc[i] = __builtin_amdgcn_mfma_f32_16x16x32_bf16(a2[kqf], bf, yacc[i], 0, 0, 0);
            }
        }
        buf ^= 1;
    }

    float* Yg = Y + (size_t)fg*MQ_*256;
    #pragma unroll
    for (int i = 0; i < 4; ++i) {
        const int j = (wn*4 + i)*16 + m16;
        const float b2v = (fg == 0) ? b2[j] : 0.f;
        #pragma unroll
        for (int r = 0; r < 4; ++r) {
            const int m = m0 + mt*16 + g*4 + r;
            if (m < MQ_) Yg[(size_t)m*256 + j] = yacc[i][r] + b2v;
        }
    }
}

// ---------------- deformable sampling ----------------
__global__ __launch_bounds__(256)
void msda_k(const float* __restrict__ off,
            const float* __restrict__ attnlog,
            const float* __restrict__ refp,
            const __hip_bfloat16* __restrict__ value,
            float* __restrict__ out)
{
    const int m = blockIdx.x;
    const int b = m & 3;
    const int d = threadIdx.x;
    const int h = d >> 5;

    __shared__ float s_off[256];
    __shared__ float s_al[128];
    __shared__ float s_ref[NL_*2];
    s_off[d] = off[(size_t)m*256 + d];
    if (d < 128) s_al[d] = attnlog[(size_t)m*128 + d];
    if (d < NL_*2) s_ref[d] = refp[(size_t)m*(NL_*2) + d];
    __syncthreads();

    float mx = -1e30f;
    #pragma unroll
    for (int t = 0; t < 16; ++t) mx = fmaxf(mx, s_al[h*16 + t]);
    float e[16], ssum = 0.f;
    #pragma unroll
    for (int t = 0; t < 16; ++t) { e[t] = __expf(s_al[h*16 + t] - mx); ssum += e[t]; }
    const float inv = 1.f / ssum;

    const int HS[4] = {128, 64, 32, 16};
    const int ST[4] = {0, 16384, 20480, 21504};

    float acc = 0.f;
    #pragma unroll
    for (int l = 0; l < NL_; ++l) {
        const int H = HS[l], W = HS[l], st = ST[l];
        const float rx = s_ref[l*2+0], ry = s_ref[l*2+1];
        #pragma unroll
        for (int p = 0; p < NP_; ++p) {
            const int base = ((h*NL_ + l)*NP_ + p);
            const float a  = e[l*4 + p] * inv;
            const float ox = s_off[base*2+0], oy = s_off[base*2+1];
            const float x = rx*(float)W + ox - 0.5f;
            const float y = ry*(float)H + oy - 0.5f;
            const float x0f = floorf(x), y0f = floorf(y);
            const int x0 = (int)x0f, y0 = (int)y0f;
            const float wx1 = x - x0f, wy1 = y - y0f;
            const float wx0 = 1.f - wx1, wy0 = 1.f - wy1;
            #pragma unroll
            for (int t = 0; t < 4; ++t) {
                const int xi = x0 + (t & 1);
                const int yi = y0 + (t >> 1);
                const float wgt = (t==0 ? wx0*wy0 : t==1 ? wx1*wy0 : t==2 ? wx0*wy1 : wx1*wy1);
                if (xi >= 0 && xi < W && yi >= 0 && yi < H) {
                    const size_t idx = (size_t)(st + yi*W + xi);
                    const float v = __bfloat162float(value[(idx*B_ + b)*D_ + d]);
                    acc = fmaf(a*wgt, v, acc);
                }
            }
        }
    }
    out[(size_t)m*256 + d] = acc;
}

// ---------------- fused add + LayerNorm ----------------
__global__ __launch_bounds__(256)
void add_ln_k(const float* __restrict__ x, const float* __restrict__ r,
              const float* __restrict__ g, const float* __restrict__ be,
              float* __restrict__ out)
{
    const int m = blockIdx.x, d = threadIdx.x;
    const float v = x[(size_t)m*D_ + d] + r[(size_t)m*D_ + d];
    float s1 = v, s2 = v*v;
    #pragma unroll
    for (int o = 32; o >= 1; o >>= 1) {
        s1 += __shfl_xor(s1, o, 64);
        s2 += __shfl_xor(s2, o, 64);
    }
    __shared__ float r1[4], r2[4];
    const int w = d >> 6;
    if ((d & 63) == 0) { r1[w] = s1; r2[w] = s2; }
    __syncthreads();
    const float t1 = r1[0]+r1[1]+r1[2]+r1[3];
    const float t2 = r2[0]+r2[1]+r2[2]+r2[3];
    const float mu  = t1 * (1.f/D_);
    const float var = t2 * (1.f/D_) - mu*mu;
    const float is  = rsqrtf(var + 1e-5f);
    out[(size_t)m*D_ + d] = (v - mu) * is * g[d] + be[d];
}

// ---- final LN: out = LN(t + y0+y1+y2+y3) ----
__global__ __launch_bounds__(256)
void add_ln4_k(const float* __restrict__ yp, const float* __restrict__ r,
               const float* __restrict__ g, const float* __restrict__ be,
               float* __restrict__ out)
{
    const int m = blockIdx.x, d = threadIdx.x;
    const size_t S = (size_t)MQ_*256, o = (size_t)m*D_ + d;
    const float v = r[o] + yp[o] + yp[S+o] + yp[2*S+o] + yp[3*S+o];
    float s1 = v, s2 = v*v;
    #pragma unroll
    for (int of = 32; of >= 1; of >>= 1) {
        s1 += __shfl_xor(s1, of, 64);
        s2 += __shfl_xor(s2, of, 64);
    }
    __shared__ float r1[4], r2[4];
    const int w = d >> 6;
    if ((d & 63) == 0) { r1[w] = s1; r2[w] = s2; }
    __syncthreads();
    const float t1 = r1[0]+r1[1]+r1[2]+r1[3];
    const float t2 = r2[0]+r2[1]+r2[2]+r2[3];
    const float mu  = t1 * (1.f/D_);
    const float var = t2 * (1.f/D_) - mu*mu;
    const float is  = rsqrtf(var + 1e-5f);
    out[o] = (v - mu) * is * g[d] + be[d];
}

extern "C" void kernel_launch(void* const* d_in, const int* in_sizes, int n_in,
                              void* d_out, int out_size, void* d_ws, size_t ws_size,
                              hipStream_t stream)
{
    const float* tgt    = (const float*)d_in[0];
    const float* refp   = (const float*)d_in[1];
    const float* mem    = (const float*)d_in[2];
    const float* W_off  = (const float*)d_in[3];
    const float* b_off  = (const float*)d_in[4];
    const float* W_attn = (const float*)d_in[5];
    const float* b_attn = (const float*)d_in[6];
    const float* W_val  = (const float*)d_in[7];
    const float* b_val  = (const float*)d_in[8];
    const float* W_out  = (const float*)d_in[9];
    const float* b_out  = (const float*)d_in[10];
    const float* ln1g   = (const float*)d_in[11];
    const float* ln1b   = (const float*)d_in[12];
    const float* W1     = (const float*)d_in[13];
    const float* b1     = (const float*)d_in[14];
    const float* W2     = (const float*)d_in[15];
    const float* b2     = (const float*)d_in[16];
    const float* ln3g   = (const float*)d_in[17];
    const float* ln3b   = (const float*)d_in[18];
    const unsigned char* mask = (const unsigned char*)d_in[21];
    float* out = (float*)d_out;

    char* p = (char*)d_ws;
    __hip_bfloat16* value = (__hip_bfloat16*)p; p += (size_t)MV_*D_*2;   // 44.6 MB (aliases A-image)
    float* offb = (float*)p; p += (size_t)MQ_*256*4;
    float* attl = (float*)p; p += (size_t)MQ_*128*4;
    float* msda = (float*)p; p += (size_t)MQ_*256*4;
    float* ca   = (float*)p; p += (size_t)MQ_*256*4;
    float* tb   = (float*)p; p += (size_t)MQ_*256*4;
    float* ypart= (float*)p; p += (size_t)4*MQ_*256*4;                   // 14.7 MB
    unsigned char* wimg   = (unsigned char*)p; p += 131072;              // W_val swizzled image
    unsigned char* qkvimg = (unsigned char*)p; p += 196608;              // W_off|W_attn frag image
    unsigned char* outimg = (unsigned char*)p; p += 131072;              // W_out frag image
    unsigned char* w1img  = (unsigned char*)p; p += 524288;              // W1 frag image
    unsigned char* w2img  = (unsigned char*)p; p += 524288;              // W2 frag image
    (void)ws_size; (void)in_sizes; (void)n_in; (void)out_size;

    unsigned char* aimg = (unsigned char*)value;   // in-place alias (block-private windows)

    // 0) weight images
    wconv_k<<<dim3(64), dim3(256), 0, stream>>>(W_val, wimg);
    wprep_k<<<dim3(336), dim3(256), 0, stream>>>(W_off, W_attn, W_out, W1, W2,
                                                 qkvimg, outimg, w1img, w2img);
    aconv_k<<<dim3((MV_*256/8)/256), dim3(256), 0, stream>>>(mem, aimg);
    // 1) value projection (bf16 MFMA)
    val_gemm_k<<<dim3(MV_/128), dim3(512), 0, stream>>>(aimg, wimg, b_val,
                                                        (unsigned short*)value, mask);
    // 2+3) off + attn logits, fused
    qkv_k<<<dim3(MQ_/16), dim3(512), 0, stream>>>(tgt, qkvimg, b_off, b_attn, offb, attl);
    // 4) deformable sampling
    msda_k<<<dim3(MQ_), dim3(256), 0, stream>>>(offb, attl, refp, value, msda);
    // 5) ca = msda @ W_out^T + b_out
    out_k<<<dim3(MQ_/16), dim3(512), 0, stream>>>(msda, outimg, b_out, ca);
    // 6) t = LN(tgt + ca)
    add_ln_k<<<dim3(MQ_), dim3(256), 0, stream>>>(ca, tgt, ln1g, ln1b, tb);
    // 7+8) FFN fused, f-split x4
    ffn_k<<<dim3((MQ_+31)/32, 4), dim3(512), 0, stream>>>(tb, w1img, b1, w2img, b2, ypart);
    // 9) out = LN(t + sum(y-partials))
    add_ln4_k<<<dim3(MQ_), dim3(256), 0, stream>>>(ypart, tb, ln3g, ln3b, out);
}

// Round 8
// 133.650 us; speedup vs baseline: 1.7314x; 1.0946x over previous
//
#include <hip/hip_runtime.h>
#include <hip/hip_bf16.h>

#define B_   4
#define LQ_  900
#define D_   256
#define NH_  8
#define DH_  32
#define NL_  4
#define NP_  4
#define DFF_ 1024
#define LIN_ 21760
#define MQ_  (LQ_*B_)    // 3600
#define MV_  (LIN_*B_)   // 87040

typedef __attribute__((ext_vector_type(8))) short bh8;
typedef __attribute__((ext_vector_type(4))) float f32x4;

__device__ __forceinline__ short bf16b(float f) {
    __hip_bfloat16 h = __float2bfloat16(f);
    return *reinterpret_cast<short*>(&h);
}

__device__ __forceinline__ void gload_lds16(const void* g, void* l) {
    __builtin_amdgcn_global_load_lds(
        (const __attribute__((address_space(1))) unsigned int*)g,
        (__attribute__((address_space(3))) unsigned int*)l, 16, 0, 0);
}

__device__ __forceinline__ bh8 af_from_f32(const float* p) {
    float4 v0 = *reinterpret_cast<const float4*>(p);
    float4 v1 = *reinterpret_cast<const float4*>(p + 4);
    return (bh8){ bf16b(v0.x), bf16b(v0.y), bf16b(v0.z), bf16b(v0.w),
                  bf16b(v1.x), bf16b(v1.y), bf16b(v1.z), bf16b(v1.w) };
}

// ---- W_val -> bf16 image: 4 k-chunks of 32 KB, rows XOR-swizzled ----
__global__ __launch_bounds__(256)
void wconv_k(const float* __restrict__ W, unsigned char* __restrict__ img)
{
    const int idx = blockIdx.x*256 + threadIdx.x;
    const int n  = idx >> 6;
    const int k0 = (idx & 63) * 4;
    const int kt = k0 >> 6;
    const int k2 = k0 & 63;
    float4 v = *reinterpret_cast<const float4*>(&W[(size_t)n*256 + k0]);
    short4 s = { bf16b(v.x), bf16b(v.y), bf16b(v.z), bf16b(v.w) };
    const int off = kt*32768 + ((n*128 + k2*2) ^ ((n & 7) << 4));
    *reinterpret_cast<short4*>(img + off) = s;
}

// ---- other weights -> MFMA B-frag images ----
__global__ __launch_bounds__(256)
void wprep_k(const float* __restrict__ Woff, const float* __restrict__ Wattn,
             const float* __restrict__ Wout, const float* __restrict__ W1,
             const float* __restrict__ W2,
             unsigned char* __restrict__ qkvimg, unsigned char* __restrict__ outimg,
             unsigned char* __restrict__ w1img, unsigned char* __restrict__ w2img)
{
    const int cid = blockIdx.x*256 + threadIdx.x;   // 86016 total
    const float* W; unsigned char* img; int KQ, c;
    if      (cid < 8192)  { W=Woff;  img=qkvimg;           KQ=8;  c=cid;       }
    else if (cid < 12288) { W=Wattn; img=qkvimg + 131072;  KQ=8;  c=cid-8192;  }
    else if (cid < 20480) { W=Wout;  img=outimg;           KQ=8;  c=cid-12288; }
    else if (cid < 53248) { W=W1;    img=w1img;            KQ=8;  c=cid-20480; }
    else                  { W=W2;    img=w2img;            KQ=32; c=cid-53248; }
    const int K   = KQ*32;
    const int n16 = c & 15, g = (c>>4)&3, t = c>>6;
    const int kq  = t & (KQ-1);
    const int ntile = t >> ((KQ==8) ? 3 : 5);
    const int n = ntile*16 + n16, k0 = kq*32 + g*8;
    float4 v0 = *reinterpret_cast<const float4*>(&W[(size_t)n*K + k0]);
    float4 v1 = *reinterpret_cast<const float4*>(&W[(size_t)n*K + k0 + 4]);
    union { short s[8]; uint4 u; } pk;
    pk.s[0]=bf16b(v0.x); pk.s[1]=bf16b(v0.y); pk.s[2]=bf16b(v0.z); pk.s[3]=bf16b(v0.w);
    pk.s[4]=bf16b(v1.x); pk.s[5]=bf16b(v1.y); pk.s[6]=bf16b(v1.z); pk.s[7]=bf16b(v1.w);
    *reinterpret_cast<uint4*>(img + (size_t)(ntile*KQ + kq)*1024 + (g*16+n16)*16) = pk.u;
}

// ---------------- value GEMM: fp32-A direct staging (pre-swizzled source), bf16 W image ----------------
// 128x256 tile, BK=64, 512 thr (8 waves 2x4). LDS: A fp32 32 KB + W bf16 32 KB.
__global__ __launch_bounds__(512)
void val_gemm_k(const float* __restrict__ A, const unsigned char* __restrict__ Wimg,
                const float* __restrict__ bias, unsigned short* __restrict__ C,
                const unsigned char* __restrict__ mask)
{
    __shared__ __align__(16) unsigned char Al[32768];   // fp32, rows 256 B, XOR-swizzled
    __shared__ __align__(16) unsigned char Wl[32768];   // bf16 image

    const int tid  = threadIdx.x;
    const int lane = tid & 63;
    const int wid  = tid >> 6;
    const int wr   = wid >> 2;
    const int wc   = wid & 3;
    const int m0   = blockIdx.x * 128;
    const int r16  = lane & 15;
    const int g    = lane >> 4;

    f32x4 acc[4][4];
    #pragma unroll
    for (int i = 0; i < 4; ++i)
        #pragma unroll
        for (int j = 0; j < 4; ++j) acc[i][j] = (f32x4){0.f,0.f,0.f,0.f};

    // per-thread staging geometry: 4 x 16 B of A (pre-swizzled source), 4 x 16 B of W (linear)
    int a_srcoff[4], a_ldsoff[4];
    #pragma unroll
    for (int s = 0; s < 4; ++s) {
        const int off = s*8192 + tid*16;          // linear LDS offset
        const int row = off >> 8;
        const int c4  = (off & 255) ^ ((row & 7) << 4);
        a_ldsoff[s] = off;
        a_srcoff[s] = (m0 + row)*1024 + c4;       // + kt*256 at issue time
    }

    for (int kt = 0; kt < 4; ++kt) {
        __syncthreads();   // previous compute's LDS readers done
        {
            const unsigned char* ab = (const unsigned char*)A + kt*256;
            #pragma unroll
            for (int s = 0; s < 4; ++s)
                gload_lds16(ab + a_srcoff[s], (char*)Al + a_ldsoff[s]);
            const unsigned char* wsrc = Wimg + kt*32768 + wid*4096 + lane*16;
            char* wdst = (char*)Wl + wid*4096 + lane*16;
            #pragma unroll
            for (int j = 0; j < 4; ++j) gload_lds16(wsrc + j*1024, wdst + j*1024);
        }
        __syncthreads();   // vmcnt(0) drain -> tiles resident
        #pragma unroll
        for (int kk = 0; kk < 2; ++kk) {
            bh8 af[4], bf[4];
            #pragma unroll
            for (int mf = 0; mf < 4; ++mf) {
                const int row = wr*64 + mf*16 + r16;
                const int swz = (row & 7) << 4;
                const int cb  = kk*128 + g*32;
                float4 v0 = *reinterpret_cast<const float4*>(Al + row*256 + ((cb     ) ^ swz));
                float4 v1 = *reinterpret_cast<const float4*>(Al + row*256 + ((cb + 16) ^ swz));
                af[mf] = (bh8){ bf16b(v0.x), bf16b(v0.y), bf16b(v0.z), bf16b(v0.w),
                                bf16b(v1.x), bf16b(v1.y), bf16b(v1.z), bf16b(v1.w) };
            }
            const int kb = kk*64 + g*16;
            #pragma unroll
            for (int nf = 0; nf < 4; ++nf) {
                const int col = wc*64 + nf*16 + r16;
                bf[nf] = *reinterpret_cast<const bh8*>(Wl + ((col*128 + kb) ^ ((col & 7) << 4)));
            }
            #pragma unroll
            for (int mf = 0; mf < 4; ++mf)
                #pragma unroll
                for (int nf = 0; nf < 4; ++nf)
                    acc[mf][nf] = __builtin_amdgcn_mfma_f32_16x16x32_bf16(af[mf], bf[nf], acc[mf][nf], 0, 0, 0);
        }
    }

    float bv[4];
    #pragma unroll
    for (int nf = 0; nf < 4; ++nf) bv[nf] = bias[wc*64 + nf*16 + r16];

    #pragma unroll
    for (int mf = 0; mf < 4; ++mf) {
        #pragma unroll
        for (int r = 0; r < 4; ++r) {
            const int gm = m0 + wr*64 + mf*16 + g*4 + r;
            const bool z = mask[(gm & 3)*LIN_ + (gm >> 2)] != 0;
            #pragma unroll
            for (int nf = 0; nf < 4; ++nf) {
                float v = acc[mf][nf][r] + bv[nf];
                if (z) v = 0.f;
                C[(size_t)gm*256 + wc*64 + nf*16 + r16] = (unsigned short)bf16b(v);
            }
        }
    }
}

// ---------------- fused off+attn projections ----------------
__global__ __launch_bounds__(512)
void qkv_k(const float* __restrict__ A, const unsigned char* __restrict__ Wimg,
           const float* __restrict__ b_off, const float* __restrict__ b_attn,
           float* __restrict__ Yoff, float* __restrict__ Yattn)
{
    const int tid = threadIdx.x, lane = tid & 63, w = tid >> 6;
    const int m16 = lane & 15, g = lane >> 4;
    const int m0 = blockIdx.x * 16;

    bh8 af[8];
    #pragma unroll
    for (int kq = 0; kq < 8; ++kq)
        af[kq] = af_from_f32(&A[(size_t)(m0 + m16)*256 + kq*32 + g*8]);

    f32x4 acc[3];
    #pragma unroll
    for (int i = 0; i < 3; ++i) acc[i] = (f32x4){0.f,0.f,0.f,0.f};

    #pragma unroll
    for (int i = 0; i < 3; ++i) {
        const int nt = w*3 + i;
        #pragma unroll
        for (int kq = 0; kq < 8; ++kq) {
            bh8 bf = *reinterpret_cast<const bh8*>(Wimg + (size_t)(nt*8 + kq)*1024 + lane*16);
            acc[i] = __builtin_amdgcn_mfma_f32_16x16x32_bf16(af[kq], bf, acc[i], 0, 0, 0);
        }
    }

    #pragma unroll
    for (int i = 0; i < 3; ++i) {
        const int nt = w*3 + i;
        const int j  = nt*16 + m16;
        #pragma unroll
        for (int r = 0; r < 4; ++r) {
            const int m = m0 + g*4 + r;
            if (nt < 16) Yoff[(size_t)m*256 + j] = acc[i][r] + b_off[j];
            else         Yattn[(size_t)m*128 + (j-256)] = acc[i][r] + b_attn[j-256];
        }
    }
}

// ---------------- out-proj + add-tgt + LN1 fused -> tb ----------------
__global__ __launch_bounds__(512)
void outln_k(const float* __restrict__ A, const unsigned char* __restrict__ Wimg,
             const float* __restrict__ bias, const float* __restrict__ res,
             const float* __restrict__ lg, const float* __restrict__ lb,
             float* __restrict__ T)
{
    __shared__ float sln[16][256];

    const int tid = threadIdx.x, lane = tid & 63, w = tid >> 6;
    const int m16 = lane & 15, g = lane >> 4;
    const int m0 = blockIdx.x * 16;

    bh8 af[8];
    #pragma unroll
    for (int kq = 0; kq < 8; ++kq)
        af[kq] = af_from_f32(&A[(size_t)(m0 + m16)*256 + kq*32 + g*8]);

    f32x4 acc[2];
    acc[0] = (f32x4){0.f,0.f,0.f,0.f};
    acc[1] = (f32x4){0.f,0.f,0.f,0.f};

    #pragma unroll
    for (int i = 0; i < 2; ++i) {
        const int nt = w*2 + i;
        #pragma unroll
        for (int kq = 0; kq < 8; ++kq) {
            bh8 bf = *reinterpret_cast<const bh8*>(Wimg + (size_t)(nt*8 + kq)*1024 + lane*16);
            acc[i] = __builtin_amdgcn_mfma_f32_16x16x32_bf16(af[kq], bf, acc[i], 0, 0, 0);
        }
    }

    #pragma unroll
    for (int i = 0; i < 2; ++i) {
        const int nt = w*2 + i;
        const int j  = nt*16 + m16;
        #pragma unroll
        for (int r = 0; r < 4; ++r) {
            const int ml = g*4 + r;
            sln[ml][j] = acc[i][r] + bias[j] + res[(size_t)(m0 + ml)*256 + j];
        }
    }
    __syncthreads();

    // LN: 32 lanes per row (tid>>5 = row), 8 cols per lane
    const int row = tid >> 5, l2 = tid & 31;
    float v[8], s1 = 0.f, s2 = 0.f;
    #pragma unroll
    for (int c = 0; c < 8; ++c) {
        v[c] = sln[row][l2 + c*32];
        s1 += v[c]; s2 += v[c]*v[c];
    }
    #pragma unroll
    for (int o = 16; o >= 1; o >>= 1) {
        s1 += __shfl_xor(s1, o, 64);
        s2 += __shfl_xor(s2, o, 64);
    }
    const float mu  = s1 * (1.f/256.f);
    const float var = s2 * (1.f/256.f) - mu*mu;
    const float is  = rsqrtf(var + 1e-5f);
    #pragma unroll
    for (int c = 0; c < 8; ++c) {
        const int j = l2 + c*32;
        T[(size_t)(m0 + row)*256 + j] = (v[c] - mu) * is * lg[j] + lb[j];
    }
}

// ---------------- fused FFN (f-split 4) ----------------
__global__ __launch_bounds__(512)
void ffn_k(const float* __restrict__ T, const unsigned char* __restrict__ W1img,
           const float* __restrict__ b1, const unsigned char* __restrict__ W2img,
           const float* __restrict__ b2, float* __restrict__ Y)
{
    __shared__ __align__(16) short hl[2][32*72];

    const int tid = threadIdx.x, lane = tid & 63, w = tid >> 6;
    const int m16 = lane & 15, g = lane >> 4;
    const int mt = w & 1, wn = w >> 1;
    const int m0 = blockIdx.x * 32;
    const int fg = blockIdx.y;

    bh8 af1[8];
    #pragma unroll
    for (int kq = 0; kq < 8; ++kq) {
        int gm = m0 + mt*16 + m16; if (gm > MQ_-1) gm = MQ_-1;
        af1[kq] = af_from_f32(&T[(size_t)gm*256 + kq*32 + g*8]);
    }

    f32x4 yacc[4];
    #pragma unroll
    for (int i = 0; i < 4; ++i) yacc[i] = (f32x4){0.f,0.f,0.f,0.f};

    int buf = 0;
    #pragma unroll
    for (int fc = 0; fc < 4; ++fc) {
        const int ftile_g = fg*16 + fc*4 + wn;
        f32x4 hacc = (f32x4){0.f,0.f,0.f,0.f};
        #pragma unroll
        for (int kq = 0; kq < 8; ++kq) {
            bh8 bf = *reinterpret_cast<const bh8*>(W1img + (size_t)(ftile_g*8 + kq)*1024 + lane*16);
            hacc = __builtin_amdgcn_mfma_f32_16x16x32_bf16(af1[kq], bf, hacc, 0, 0, 0);
        }
        const float bb = b1[ftile_g*16 + m16];
        #pragma unroll
        for (int r = 0; r < 4; ++r) {
            const float v = fmaxf(hacc[r] + bb, 0.f);
            *reinterpret_cast<short*>((char*)&hl[buf][0]
                + (mt*16 + g*4 + r)*144 + (wn*16 + m16)*2) = bf16b(v);
        }
        __syncthreads();
        bh8 a2[2];
        #pragma unroll
        for (int kqf = 0; kqf < 2; ++kqf)
            a2[kqf] = *reinterpret_cast<const bh8*>((char*)&hl[buf][0]
                + (mt*16 + m16)*144 + (kqf*32 + g*8)*2);
        #pragma unroll
        for (int i = 0; i < 4; ++i) {
            const int nt = wn*4 + i;
            #pragma unroll
            for (int kqf = 0; kqf < 2; ++kqf) {
                const int kq2 = fg*8 + fc*2 + kqf;
                bh8 bf = *reinterpret_cast<const bh8*>(W2img + (size_t)(nt*32 + kq2)*1024 + lane*16);
                yacc[i] = __builtin_amdgcn_mfma_f32_16x16x32_bf16(a2[kqf], bf, yacc[i], 0, 0, 0);
            }
        }
        buf ^= 1;
    }

    float* Yg = Y + (size_t)fg*MQ_*256;
    #pragma unroll
    for (int i = 0; i < 4; ++i) {
        const int j = (wn*4 + i)*16 + m16;
        const float b2v = (fg == 0) ? b2[j] : 0.f;
        #pragma unroll
        for (int r = 0; r < 4; ++r) {
            const int m = m0 + mt*16 + g*4 + r;
            if (m < MQ_) Yg[(size_t)m*256 + j] = yacc[i][r] + b2v;
        }
    }
}

// ---------------- deformable sampling ----------------
__global__ __launch_bounds__(256)
void msda_k(const float* __restrict__ off,
            const float* __restrict__ attnlog,
            const float* __restrict__ refp,
            const __hip_bfloat16* __restrict__ value,
            float* __restrict__ out)
{
    const int m = blockIdx.x;
    const int b = m & 3;
    const int d = threadIdx.x;
    const int h = d >> 5;

    __shared__ float s_off[256];
    __shared__ float s_al[128];
    __shared__ float s_ref[NL_*2];
    s_off[d] = off[(size_t)m*256 + d];
    if (d < 128) s_al[d] = attnlog[(size_t)m*128 + d];
    if (d < NL_*2) s_ref[d] = refp[(size_t)m*(NL_*2) + d];
    __syncthreads();

    float mx = -1e30f;
    #pragma unroll
    for (int t = 0; t < 16; ++t) mx = fmaxf(mx, s_al[h*16 + t]);
    float e[16], ssum = 0.f;
    #pragma unroll
    for (int t = 0; t < 16; ++t) { e[t] = __expf(s_al[h*16 + t] - mx); ssum += e[t]; }
    const float inv = 1.f / ssum;

    const int HS[4] = {128, 64, 32, 16};
    const int ST[4] = {0, 16384, 20480, 21504};

    float acc = 0.f;
    #pragma unroll
    for (int l = 0; l < NL_; ++l) {
        const int H = HS[l], W = HS[l], st = ST[l];
        const float rx = s_ref[l*2+0], ry = s_ref[l*2+1];
        #pragma unroll
        for (int p = 0; p < NP_; ++p) {
            const int base = ((h*NL_ + l)*NP_ + p);
            const float a  = e[l*4 + p] * inv;
            const float ox = s_off[base*2+0], oy = s_off[base*2+1];
            const float x = rx*(float)W + ox - 0.5f;
            const float y = ry*(float)H + oy - 0.5f;
            const float x0f = floorf(x), y0f = floorf(y);
            const int x0 = (int)x0f, y0 = (int)y0f;
            const float wx1 = x - x0f, wy1 = y - y0f;
            const float wx0 = 1.f - wx1, wy0 = 1.f - wy1;
            #pragma unroll
            for (int t = 0; t < 4; ++t) {
                const int xi = x0 + (t & 1);
                const int yi = y0 + (t >> 1);
                const float wgt = (t==0 ? wx0*wy0 : t==1 ? wx1*wy0 : t==2 ? wx0*wy1 : wx1*wy1);
                if (xi >= 0 && xi < W && yi >= 0 && yi < H) {
                    const size_t idx = (size_t)(st + yi*W + xi);
                    const float v = __bfloat162float(value[(idx*B_ + b)*D_ + d]);
                    acc = fmaf(a*wgt, v, acc);
                }
            }
        }
    }
    out[(size_t)m*256 + d] = acc;
}

// ---- final LN: out = LN(t + y0+y1+y2+y3) ----
__global__ __launch_bounds__(256)
void add_ln4_k(const float* __restrict__ yp, const float* __restrict__ r,
               const float* __restrict__ g, const float* __restrict__ be,
               float* __restrict__ out)
{
    const int m = blockIdx.x, d = threadIdx.x;
    const size_t S = (size_t)MQ_*256, o = (size_t)m*D_ + d;
    const float v = r[o] + yp[o] + yp[S+o] + yp[2*S+o] + yp[3*S+o];
    float s1 = v, s2 = v*v;
    #pragma unroll
    for (int of = 32; of >= 1; of >>= 1) {
        s1 += __shfl_xor(s1, of, 64);
        s2 += __shfl_xor(s2, of, 64);
    }
    __shared__ float r1[4], r2[4];
    const int w = d >> 6;
    if ((d & 63) == 0) { r1[w] = s1; r2[w] = s2; }
    __syncthreads();
    const float t1 = r1[0]+r1[1]+r1[2]+r1[3];
    const float t2 = r2[0]+r2[1]+r2[2]+r2[3];
    const float mu  = t1 * (1.f/D_);
    const float var = t2 * (1.f/D_) - mu*mu;
    const float is  = rsqrtf(var + 1e-5f);
    out[o] = (v - mu) * is * g[d] + be[d];
}

extern "C" void kernel_launch(void* const* d_in, const int* in_sizes, int n_in,
                              void* d_out, int out_size, void* d_ws, size_t ws_size,
                              hipStream_t stream)
{
    const float* tgt    = (const float*)d_in[0];
    const float* refp   = (const float*)d_in[1];
    const float* mem    = (const float*)d_in[2];
    const float* W_off  = (const float*)d_in[3];
    const float* b_off  = (const float*)d_in[4];
    const float* W_attn = (const float*)d_in[5];
    const float* b_attn = (const float*)d_in[6];
    const float* W_val  = (const float*)d_in[7];
    const float* b_val  = (const float*)d_in[8];
    const float* W_out  = (const float*)d_in[9];
    const float* b_out  = (const float*)d_in[10];
    const float* ln1g   = (const float*)d_in[11];
    const float* ln1b   = (const float*)d_in[12];
    const float* W1     = (const float*)d_in[13];
    const float* b1     = (const float*)d_in[14];
    const float* W2     = (const float*)d_in[15];
    const float* b2     = (const float*)d_in[16];
    const float* ln3g   = (const float*)d_in[17];
    const float* ln3b   = (const float*)d_in[18];
    const unsigned char* mask = (const unsigned char*)d_in[21];
    float* out = (float*)d_out;

    char* p = (char*)d_ws;
    __hip_bfloat16* value = (__hip_bfloat16*)p; p += (size_t)MV_*D_*2;   // 44.6 MB
    float* offb = (float*)p; p += (size_t)MQ_*256*4;
    float* attl = (float*)p; p += (size_t)MQ_*128*4;
    float* msda = (float*)p; p += (size_t)MQ_*256*4;
    float* tb   = (float*)p; p += (size_t)MQ_*256*4;
    float* ypart= (float*)p; p += (size_t)4*MQ_*256*4;                   // 14.7 MB
    unsigned char* wimg   = (unsigned char*)p; p += 131072;
    unsigned char* qkvimg = (unsigned char*)p; p += 196608;
    unsigned char* outimg = (unsigned char*)p; p += 131072;
    unsigned char* w1img  = (unsigned char*)p; p += 524288;
    unsigned char* w2img  = (unsigned char*)p; p += 524288;
    (void)ws_size; (void)in_sizes; (void)n_in; (void)out_size;

    // 0) weight images
    wconv_k<<<dim3(64), dim3(256), 0, stream>>>(W_val, wimg);
    wprep_k<<<dim3(336), dim3(256), 0, stream>>>(W_off, W_attn, W_out, W1, W2,
                                                 qkvimg, outimg, w1img, w2img);
    // 1) value projection: fp32-A direct + W image
    val_gemm_k<<<dim3(MV_/128), dim3(512), 0, stream>>>(mem, wimg, b_val,
                                                        (unsigned short*)value, mask);
    // 2+3) off + attn logits, fused
    qkv_k<<<dim3(MQ_/16), dim3(512), 0, stream>>>(tgt, qkvimg, b_off, b_attn, offb, attl);
    // 4) deformable sampling
    msda_k<<<dim3(MQ_), dim3(256), 0, stream>>>(offb, attl, refp, value, msda);
    // 5+6) ca = msda @ W_out^T + b_out ; tb = LN(tgt + ca)   (fused)
    outln_k<<<dim3(MQ_/16), dim3(512), 0, stream>>>(msda, outimg, b_out, tgt, ln1g, ln1b, tb);
    // 7+8) FFN fused, f-split x4
    ffn_k<<<dim3((MQ_+31)/32, 4), dim3(512), 0, stream>>>(tb, w1img, b1, w2img, b2, ypart);
    // 9) out = LN(t + sum(y-partials))
    add_ln4_k<<<dim3(MQ_), dim3(256), 0, stream>>>(ypart, tb, ln3g, ln3b, out);
}